// Round 4
// baseline (183.019 us; speedup 1.0000x reference)
//
#include <hip/hip_runtime.h>
#include <hip/hip_bf16.h>

typedef __attribute__((ext_vector_type(8))) short short8;
typedef __attribute__((ext_vector_type(4))) float f32x4;

#define LDST 72   // bf16 elements per LDS row (144B)
#define NW 4      // windows per block (software pipeline depth)
#define MFMA16(a, b, c) __builtin_amdgcn_mfma_f32_16x16x32_bf16(a, b, c, 0, 0, 0)

// LDS-only barrier: all inter-wave deps in this kernel are through LDS, so we
// drain lgkmcnt but NOT vmcnt -> prefetch loads + output stores stay in flight
// across barriers (unlike __syncthreads, which emits s_waitcnt vmcnt(0)).
#define BARLDS() asm volatile("s_waitcnt lgkmcnt(0)\n\ts_barrier" ::: "memory")

// One block = one batch x 4 consecutive windows, pipelined: while window j is
// computed from LDS, window j+1's Q/K/V are loading into registers (T14).
// 256 threads = 4 waves; wave w owns rows m0=w*16..+15 of each window.
// Roll(-32) folded into the global row index p=(n*64+32+i)&8191.
__global__ __launch_bounds__(256, 4)
void swin64_attn(const float* __restrict__ qg, const float* __restrict__ kg,
                 const float* __restrict__ vg, const float* __restrict__ tbl,
                 float* __restrict__ ox, float* __restrict__ oa) {
  __shared__ unsigned short Khi[64 * LDST], Klo[64 * LDST];
  __shared__ unsigned short Vhi[64 * LDST];      // transposed [c][j], XOR-swizzled
  __shared__ unsigned short Pb[64 * LDST];
  __shared__ float rs[64];                       // per-row 1/sum
  __shared__ float btab[128];

  const int t = threadIdx.x;
  const int b = blockIdx.x >> 5;        // 64 batches
  const int g = blockIdx.x & 31;        // window group (4 windows each)
  const int l = t & 63;
  const int w = t >> 6;
  const int r15 = l & 15;
  const int g4 = l >> 4;
  const int m0 = w * 16;
  const int row0 = t >> 3;              // staging: rows row0, row0+32
  const int c8 = t & 7;                 // col octet
  const size_t bbase = (size_t)b * 8192;

  if (t < 127) btab[t] = tbl[t];

  // prefetch registers (raw f32; converted at stage-write time)
  float4 pk0, pk1, pk2, pk3, pv0, pv1, pv2, pv3, pq0, pq1, pq2, pq3;

  auto issueKV = [&](int n) {
    const int p0 = (n * 64 + 32 + row0) & 8191;
    const int p1 = (n * 64 + 64 + row0) & 8191;  // row0+32
    const float* k0 = kg + (bbase + p0) * 64 + c8 * 8;
    const float* k1 = kg + (bbase + p1) * 64 + c8 * 8;
    const float* v0 = vg + (bbase + p0) * 64 + c8 * 8;
    const float* v1 = vg + (bbase + p1) * 64 + c8 * 8;
    pk0 = *(const float4*)k0; pk1 = *(const float4*)(k0 + 4);
    pk2 = *(const float4*)k1; pk3 = *(const float4*)(k1 + 4);
    pv0 = *(const float4*)v0; pv1 = *(const float4*)(v0 + 4);
    pv2 = *(const float4*)v1; pv3 = *(const float4*)(v1 + 4);
  };
  auto issueQ = [&](int n) {
    const int qrow = (n * 64 + 32 + m0 + r15) & 8191;
    const float* qp = qg + (bbase + qrow) * 64 + g4 * 8;
    pq0 = *(const float4*)qp;        pq1 = *(const float4*)(qp + 4);
    pq2 = *(const float4*)(qp + 32); pq3 = *(const float4*)(qp + 36);
  };

  auto packK = [&](int row, const float4 A, const float4 B) {
    const float f[8] = {A.x, A.y, A.z, A.w, B.x, B.y, B.z, B.w};
    unsigned uh[4], ul[4];
#pragma unroll
    for (int i = 0; i < 4; ++i) {
      const unsigned u0 = __float_as_uint(f[2 * i]);
      const unsigned u1 = __float_as_uint(f[2 * i + 1]);
      const float r0 = f[2 * i]     - __uint_as_float(u0 & 0xFFFF0000u);
      const float r1 = f[2 * i + 1] - __uint_as_float(u1 & 0xFFFF0000u);
      uh[i] = (u0 >> 16) | (u1 & 0xFFFF0000u);
      ul[i] = (__float_as_uint(r0) >> 16) | (__float_as_uint(r1) & 0xFFFF0000u);
    }
    *(uint4*)&Khi[row * LDST + c8 * 8] = make_uint4(uh[0], uh[1], uh[2], uh[3]);
    *(uint4*)&Klo[row * LDST + c8 * 8] = make_uint4(ul[0], ul[1], ul[2], ul[3]);
  };
  auto packV = [&](int row, const float4 A, const float4 B) {
    const float f[8] = {A.x, A.y, A.z, A.w, B.x, B.y, B.z, B.w};
#pragma unroll
    for (int i = 0; i < 8; ++i) {
      const int c = c8 * 8 + i;          // channel -> Vt row
      const int idx = c * LDST + ((((row >> 3) ^ ((c >> 3) & 7)) << 3) | (row & 7));
      Vhi[idx] = (unsigned short)((__float_as_uint(f[i]) + 0x8000u) >> 16);
    }
  };
  auto stageWrite = [&]() {
    packK(row0, pk0, pk1);
    packK(row0 + 32, pk2, pk3);
    packV(row0, pv0, pv1);
    packV(row0 + 32, pv2, pv3);
  };

  // fragment loaders
  auto ldf = [&](const unsigned short* a, int rb, int kb) -> short8 {
    return *(const short8*)&a[(rb + r15) * LDST + kb * 32 + g4 * 8];
  };
  auto ldv = [&](const unsigned short* a, int rb, int kb) -> short8 {
    const int c = rb + r15;
    const int blk = (kb * 4 + g4) ^ ((c >> 3) & 7);
    return *(const short8*)&a[c * LDST + blk * 8];
  };

  // ---- cold start: stage window g*NW
  issueKV(g * NW);
  issueQ(g * NW);
  stageWrite();
  BARLDS();

  for (int j = 0; j < NW; ++j) {
    const int n = g * NW + j;

    // Q hi/lo trunc split from prefetch regs (before pq is re-issued)
    short8 qh0, qh1, ql0, ql1;
    {
      const float f0[8] = {pq0.x, pq0.y, pq0.z, pq0.w, pq1.x, pq1.y, pq1.z, pq1.w};
      const float f1[8] = {pq2.x, pq2.y, pq2.z, pq2.w, pq3.x, pq3.y, pq3.z, pq3.w};
#pragma unroll
      for (int i = 0; i < 8; ++i) {
        const unsigned u0 = __float_as_uint(f0[i]);
        qh0[i] = (short)(u0 >> 16);
        ql0[i] = (short)(__float_as_uint(f0[i] - __uint_as_float(u0 & 0xFFFF0000u)) >> 16);
        const unsigned u1 = __float_as_uint(f1[i]);
        qh1[i] = (short)(u1 >> 16);
        ql1[i] = (short)(__float_as_uint(f1[i] - __uint_as_float(u1 & 0xFFFF0000u)) >> 16);
      }
    }

    // issue next window's loads; they fly across the whole compute phase
    // (no barrier below drains vmcnt) and are waited at the next stageWrite.
    if (j + 1 < NW) { issueKV(n + 1); issueQ(n + 1); }

    // ---- QK^T with hi/lo split (drop lo*lo)
    f32x4 acc[4];
#pragma unroll
    for (int nt = 0; nt < 4; ++nt) {
      const short8 kh0 = ldf(Khi, nt * 16, 0), kh1 = ldf(Khi, nt * 16, 1);
      const short8 kl0 = ldf(Klo, nt * 16, 0), kl1 = ldf(Klo, nt * 16, 1);
      f32x4 a = {0.f, 0.f, 0.f, 0.f};
      a = MFMA16(qh0, kh0, a);
      a = MFMA16(qh1, kh1, a);
      a = MFMA16(ql0, kh0, a);
      a = MFMA16(ql1, kh1, a);
      a = MFMA16(qh0, kl0, a);
      a = MFMA16(qh1, kl1, a);
      acc[nt] = a;
    }

    // ---- scale + bias + mask; D layout: row = m0+g4*4+r, col = nt*16+r15
#pragma unroll
    for (int nt = 0; nt < 4; ++nt) {
#pragma unroll
      for (int r = 0; r < 4; ++r) {
        const int i = m0 + g4 * 4 + r;
        const int jj = nt * 16 + r15;
        float sx = acc[nt][r] * 0.125f + btab[i - jj + 63];
        if (n == 127 && ((i < 32) != (jj < 32))) sx -= 100.f;
        acc[nt][r] = sx;
      }
    }

    // ---- row softmax across the 16-lane row group
    float mx[4], rinv[4];
#pragma unroll
    for (int r = 0; r < 4; ++r) {
      float m2 = fmaxf(fmaxf(acc[0][r], acc[1][r]), fmaxf(acc[2][r], acc[3][r]));
      m2 = fmaxf(m2, __shfl_xor(m2, 1));
      m2 = fmaxf(m2, __shfl_xor(m2, 2));
      m2 = fmaxf(m2, __shfl_xor(m2, 4));
      m2 = fmaxf(m2, __shfl_xor(m2, 8));
      mx[r] = m2;
    }
#pragma unroll
    for (int nt = 0; nt < 4; ++nt) {
#pragma unroll
      for (int r = 0; r < 4; ++r) acc[nt][r] = __expf(acc[nt][r] - mx[r]);
    }
#pragma unroll
    for (int r = 0; r < 4; ++r) {
      float s2 = acc[0][r] + acc[1][r] + acc[2][r] + acc[3][r];
      s2 += __shfl_xor(s2, 1);
      s2 += __shfl_xor(s2, 2);
      s2 += __shfl_xor(s2, 4);
      s2 += __shfl_xor(s2, 8);
      rinv[r] = 1.f / s2;
    }

    // ---- publish P (bf16, unnormalized) + row 1/sum to LDS
#pragma unroll
    for (int nt = 0; nt < 4; ++nt) {
#pragma unroll
      for (int r = 0; r < 4; ++r) {
        const int i = m0 + g4 * 4 + r;
        const int jj = nt * 16 + r15;
        Pb[i * LDST + jj] =
            (unsigned short)((__float_as_uint(acc[nt][r]) + 0x8000u) >> 16);
      }
    }
    if (r15 == 0) {
#pragma unroll
      for (int r = 0; r < 4; ++r) rs[m0 + g4 * 4 + r] = rinv[r];
    }
    BARLDS();  // (A) P + rs visible to all waves

    // ---- PV: x = P * Vhi, normalize by rinv at the store
    const short8 pa0 = ldf(Pb, m0, 0), pa1 = ldf(Pb, m0, 1);
#pragma unroll
    for (int ct = 0; ct < 4; ++ct) {
      const short8 vh0 = ldv(Vhi, ct * 16, 0), vh1 = ldv(Vhi, ct * 16, 1);
      f32x4 a = {0.f, 0.f, 0.f, 0.f};
      a = MFMA16(pa0, vh0, a);
      a = MFMA16(pa1, vh1, a);
#pragma unroll
      for (int r = 0; r < 4; ++r) {
        const int i = m0 + g4 * 4 + r;
        const int p2 = (n * 64 + 32 + i) & 8191;
        ox[(bbase + p2) * 64 + ct * 16 + r15] = a[r] * rinv[r];
      }
    }

    // ---- attn output straight from Pb (bf16 precision is ample): 4x float4
    {
      const int er = t >> 2, ec = (t & 3) << 4;
      const float ri = rs[er];
      const uint4 u0 = *(const uint4*)&Pb[er * LDST + ec];
      const uint4 u1 = *(const uint4*)&Pb[er * LDST + ec + 8];
      float* apo = oa + ((size_t)(b * 128 + n)) * 4096 + er * 64 + ec;
      float4 o;
      o.x = __uint_as_float(u0.x << 16) * ri;
      o.y = __uint_as_float(u0.x & 0xFFFF0000u) * ri;
      o.z = __uint_as_float(u0.y << 16) * ri;
      o.w = __uint_as_float(u0.y & 0xFFFF0000u) * ri;
      *(float4*)apo = o;
      o.x = __uint_as_float(u0.z << 16) * ri;
      o.y = __uint_as_float(u0.z & 0xFFFF0000u) * ri;
      o.z = __uint_as_float(u0.w << 16) * ri;
      o.w = __uint_as_float(u0.w & 0xFFFF0000u) * ri;
      *(float4*)(apo + 4) = o;
      o.x = __uint_as_float(u1.x << 16) * ri;
      o.y = __uint_as_float(u1.x & 0xFFFF0000u) * ri;
      o.z = __uint_as_float(u1.y << 16) * ri;
      o.w = __uint_as_float(u1.y & 0xFFFF0000u) * ri;
      *(float4*)(apo + 8) = o;
      o.x = __uint_as_float(u1.z << 16) * ri;
      o.y = __uint_as_float(u1.z & 0xFFFF0000u) * ri;
      o.z = __uint_as_float(u1.w << 16) * ri;
      o.w = __uint_as_float(u1.w & 0xFFFF0000u) * ri;
      *(float4*)(apo + 12) = o;
    }

    if (j + 1 < NW) {
      BARLDS();      // (B) all LDS reads of this window done
      stageWrite();  // waits the prefetched loads (compiler-counted vmcnt)
      BARLDS();      // (C) next window's LDS visible
    }
  }
}

extern "C" void kernel_launch(void* const* d_in, const int* in_sizes, int n_in,
                              void* d_out, int out_size, void* d_ws, size_t ws_size,
                              hipStream_t stream) {
  const float* q = (const float*)d_in[0];
  const float* k = (const float*)d_in[1];
  const float* v = (const float*)d_in[2];
  const float* tbl = (const float*)d_in[3];
  float* ox = (float*)d_out;
  float* oa = ox + (size_t)64 * 8192 * 64;  // x first, then attn
  swin64_attn<<<dim3(64 * 32), dim3(256), 0, stream>>>(q, k, v, tbl, ox, oa);
}

// Round 6
// 136.202 us; speedup vs baseline: 1.3437x; 1.3437x over previous
//
#include <hip/hip_runtime.h>
#include <hip/hip_bf16.h>

typedef __attribute__((ext_vector_type(8))) short short8;
typedef __attribute__((ext_vector_type(4))) float f32x4;

#define LDST 72   // bf16 elements per LDS row (144B)
#define NW 2      // windows per block (pipeline depth)
#define MFMA16(a, b, c) __builtin_amdgcn_mfma_f32_16x16x32_bf16(a, b, c, 0, 0, 0)

// LDS-only barrier: inter-wave deps are LDS-only here; do NOT drain vmcnt so
// asm-prefetched loads (and output stores) stay in flight across barriers.
#define BARLDS() asm volatile("s_waitcnt lgkmcnt(0)\n\ts_barrier" ::: "memory")
// Asm-forced global load: cannot be sunk by the compiler (R4's failure mode).
#define GLOAD(dst, p) asm volatile("global_load_dwordx4 %0, %1, off" : "=v"(dst) : "v"(p))

// One block = one batch x NW consecutive windows. 256 threads = 4 waves; wave
// w owns rows m0=w*16..+15. Roll(-32) folded into global row p=(n*64+32+i)&8191.
// While window j is computed from LDS, window j+1's Q/K/V fly in 12 pinned
// float4 registers (issued by volatile asm before the MFMA phase).
__global__ __launch_bounds__(256, 3)
void swin64_attn(const float* __restrict__ qg, const float* __restrict__ kg,
                 const float* __restrict__ vg, const float* __restrict__ tbl,
                 float* __restrict__ ox, float* __restrict__ oa) {
  __shared__ unsigned short Khi[64 * LDST], Klo[64 * LDST];
  __shared__ unsigned short Vhi[64 * LDST];      // transposed [c][j], XOR-swizzled
  __shared__ unsigned short Pb[64 * LDST];
  __shared__ float btab[128];

  const int t = threadIdx.x;
  const int b = blockIdx.x >> 6;        // 64 batches
  const int n0 = (blockIdx.x & 63) * NW;
  const int l = t & 63;
  const int w = t >> 6;
  const int r15 = l & 15;
  const int g4 = l >> 4;
  const int m0 = w * 16;
  const int row0 = t >> 3;              // staging rows row0, row0+32
  const int c8 = t & 7;                 // col octet
  const size_t bbase = (size_t)b * 8192;

  if (t < 127) btab[t] = tbl[t];

  // pinned prefetch registers
  float4 k0, k1, k2, k3, v0, v1, v2, v3, q0, q1, q2, q3;

  auto issueAll = [&](int n) {
    const int p0 = (n * 64 + 32 + row0) & 8191;
    const int p1 = (n * 64 + 64 + row0) & 8191;
    const float* kp0 = kg + (bbase + p0) * 64 + c8 * 8;
    const float* kp1 = kg + (bbase + p1) * 64 + c8 * 8;
    const float* vp0 = vg + (bbase + p0) * 64 + c8 * 8;
    const float* vp1 = vg + (bbase + p1) * 64 + c8 * 8;
    const int qrow = (n * 64 + 32 + m0 + r15) & 8191;
    const float* qp = qg + (bbase + qrow) * 64 + g4 * 8;
    GLOAD(k0, kp0); GLOAD(k1, kp0 + 4); GLOAD(k2, kp1); GLOAD(k3, kp1 + 4);
    GLOAD(v0, vp0); GLOAD(v1, vp0 + 4); GLOAD(v2, vp1); GLOAD(v3, vp1 + 4);
    GLOAD(q0, qp);  GLOAD(q1, qp + 4);  GLOAD(q2, qp + 32); GLOAD(q3, qp + 36);
  };
  auto waitLoads = [&]() {
    // Drain the asm prefetch loads. The sched_barrier(0) immediately after is
    // rule-18's measured fence: it stops the scheduler from hoisting the
    // register-only pack/convert consumers above the waitcnt (tied-operand
    // asm is unsupported on gfx950).
    asm volatile("s_waitcnt vmcnt(0)" ::: "memory");
    __builtin_amdgcn_sched_barrier(0);
  };

  auto packK = [&](int row, const float4 A, const float4 B) {
    const float f[8] = {A.x, A.y, A.z, A.w, B.x, B.y, B.z, B.w};
    unsigned uh[4], ul[4];
#pragma unroll
    for (int i = 0; i < 4; ++i) {
      const unsigned u0 = __float_as_uint(f[2 * i]);
      const unsigned u1 = __float_as_uint(f[2 * i + 1]);
      const float r0 = f[2 * i]     - __uint_as_float(u0 & 0xFFFF0000u);
      const float r1 = f[2 * i + 1] - __uint_as_float(u1 & 0xFFFF0000u);
      uh[i] = (u0 >> 16) | (u1 & 0xFFFF0000u);
      ul[i] = (__float_as_uint(r0) >> 16) | (__float_as_uint(r1) & 0xFFFF0000u);
    }
    *(uint4*)&Khi[row * LDST + c8 * 8] = make_uint4(uh[0], uh[1], uh[2], uh[3]);
    *(uint4*)&Klo[row * LDST + c8 * 8] = make_uint4(ul[0], ul[1], ul[2], ul[3]);
  };
  auto packV = [&](int row, const float4 A, const float4 B) {
    const float f[8] = {A.x, A.y, A.z, A.w, B.x, B.y, B.z, B.w};
#pragma unroll
    for (int i = 0; i < 8; ++i) {
      const int c = c8 * 8 + i;          // channel -> Vt row
      const int idx = c * LDST + ((((row >> 3) ^ ((c >> 3) & 7)) << 3) | (row & 7));
      Vhi[idx] = (unsigned short)((__float_as_uint(f[i]) + 0x8000u) >> 16);
    }
  };
  auto stageKV = [&]() {
    packK(row0, k0, k1);
    packK(row0 + 32, k2, k3);
    packV(row0, v0, v1);
    packV(row0 + 32, v2, v3);
  };

  short8 qh0, qh1, ql0, ql1;
  auto makeQ = [&]() {
    const float f0[8] = {q0.x, q0.y, q0.z, q0.w, q1.x, q1.y, q1.z, q1.w};
    const float f1[8] = {q2.x, q2.y, q2.z, q2.w, q3.x, q3.y, q3.z, q3.w};
#pragma unroll
    for (int i = 0; i < 8; ++i) {
      const unsigned u0 = __float_as_uint(f0[i]);
      qh0[i] = (short)(u0 >> 16);
      ql0[i] = (short)(__float_as_uint(f0[i] - __uint_as_float(u0 & 0xFFFF0000u)) >> 16);
      const unsigned u1 = __float_as_uint(f1[i]);
      qh1[i] = (short)(u1 >> 16);
      ql1[i] = (short)(__float_as_uint(f1[i] - __uint_as_float(u1 & 0xFFFF0000u)) >> 16);
    }
  };

  auto ldf = [&](const unsigned short* a, int rb, int kb) -> short8 {
    return *(const short8*)&a[(rb + r15) * LDST + kb * 32 + g4 * 8];
  };
  auto ldv = [&](const unsigned short* a, int rb, int kb) -> short8 {
    const int c = rb + r15;
    const int blk = (kb * 4 + g4) ^ ((c >> 3) & 7);
    return *(const short8*)&a[c * LDST + blk * 8];
  };

  // ---- cold start: window n0
  issueAll(n0);
  waitLoads();
  stageKV();
  makeQ();
  BARLDS();

#pragma unroll
  for (int j = 0; j < NW; ++j) {
    const int n = n0 + j;

    // next window's loads fly across the whole compute phase (no vmcnt drain
    // at any barrier below)
    if (j + 1 < NW) issueAll(n + 1);

    // ---- QK^T with hi/lo split (drop lo*lo)
    f32x4 acc[4];
#pragma unroll
    for (int nt = 0; nt < 4; ++nt) {
      const short8 kh0 = ldf(Khi, nt * 16, 0), kh1 = ldf(Khi, nt * 16, 1);
      const short8 kl0 = ldf(Klo, nt * 16, 0), kl1 = ldf(Klo, nt * 16, 1);
      f32x4 a = {0.f, 0.f, 0.f, 0.f};
      a = MFMA16(qh0, kh0, a);
      a = MFMA16(qh1, kh1, a);
      a = MFMA16(ql0, kh0, a);
      a = MFMA16(ql1, kh1, a);
      a = MFMA16(qh0, kl0, a);
      a = MFMA16(qh1, kl1, a);
      acc[nt] = a;
    }

    // ---- scale + bias + mask; D layout: row = m0+g4*4+r, col = nt*16+r15
#pragma unroll
    for (int nt = 0; nt < 4; ++nt) {
#pragma unroll
      for (int r = 0; r < 4; ++r) {
        const int i = m0 + g4 * 4 + r;
        const int jj = nt * 16 + r15;
        float sx = acc[nt][r] * 0.125f + btab[i - jj + 63];
        if (n == 127 && ((i < 32) != (jj < 32))) sx -= 100.f;
        acc[nt][r] = sx;
      }
    }

    // ---- row softmax across the 16-lane row group
    float mx[4], rinv[4];
#pragma unroll
    for (int r = 0; r < 4; ++r) {
      float m2 = fmaxf(fmaxf(acc[0][r], acc[1][r]), fmaxf(acc[2][r], acc[3][r]));
      m2 = fmaxf(m2, __shfl_xor(m2, 1));
      m2 = fmaxf(m2, __shfl_xor(m2, 2));
      m2 = fmaxf(m2, __shfl_xor(m2, 4));
      m2 = fmaxf(m2, __shfl_xor(m2, 8));
      mx[r] = m2;
    }
#pragma unroll
    for (int nt = 0; nt < 4; ++nt) {
#pragma unroll
      for (int r = 0; r < 4; ++r) acc[nt][r] = __expf(acc[nt][r] - mx[r]);
    }
#pragma unroll
    for (int r = 0; r < 4; ++r) {
      float s2 = acc[0][r] + acc[1][r] + acc[2][r] + acc[3][r];
      s2 += __shfl_xor(s2, 1);
      s2 += __shfl_xor(s2, 2);
      s2 += __shfl_xor(s2, 4);
      s2 += __shfl_xor(s2, 8);
      rinv[r] = 1.f / s2;
    }

    // ---- publish P (bf16, unnormalized) + write attn (normalized f32)
    float* ap = oa + ((size_t)(b * 128 + n)) * 4096;
#pragma unroll
    for (int nt = 0; nt < 4; ++nt) {
#pragma unroll
      for (int r = 0; r < 4; ++r) {
        const int i = m0 + g4 * 4 + r;
        const int jj = nt * 16 + r15;
        Pb[i * LDST + jj] =
            (unsigned short)((__float_as_uint(acc[nt][r]) + 0x8000u) >> 16);
        ap[i * 64 + jj] = acc[nt][r] * rinv[r];
      }
    }
    BARLDS();  // (A) P visible to all waves

    // ---- PV: x = P * Vhi, normalize at the store
    const short8 pa0 = ldf(Pb, m0, 0), pa1 = ldf(Pb, m0, 1);
#pragma unroll
    for (int ct = 0; ct < 4; ++ct) {
      const short8 vh0 = ldv(Vhi, ct * 16, 0), vh1 = ldv(Vhi, ct * 16, 1);
      f32x4 a = {0.f, 0.f, 0.f, 0.f};
      a = MFMA16(pa0, vh0, a);
      a = MFMA16(pa1, vh1, a);
#pragma unroll
      for (int r = 0; r < 4; ++r) {
        const int i = m0 + g4 * 4 + r;
        const int p2 = (n * 64 + 32 + i) & 8191;
        ox[(bbase + p2) * 64 + ct * 16 + r15] = a[r] * rinv[r];
      }
    }

    if (j + 1 < NW) {
      BARLDS();      // (B) all LDS reads of this window done
      waitLoads();   // prefetched loads have flown across the compute phase
      stageKV();
      makeQ();
      BARLDS();      // (C) next window's LDS visible
    }
  }
}

extern "C" void kernel_launch(void* const* d_in, const int* in_sizes, int n_in,
                              void* d_out, int out_size, void* d_ws, size_t ws_size,
                              hipStream_t stream) {
  const float* q = (const float*)d_in[0];
  const float* k = (const float*)d_in[1];
  const float* v = (const float*)d_in[2];
  const float* tbl = (const float*)d_in[3];
  float* ox = (float*)d_out;
  float* oa = ox + (size_t)64 * 8192 * 64;  // x first, then attn
  swin64_attn<<<dim3(64 * 64), dim3(256), 0, stream>>>(q, k, v, tbl, ox, oa);
}